// Round 14
// baseline (628.864 us; speedup 1.0000x reference)
//
#include <hip/hip_runtime.h>
#include <hip/hip_cooperative_groups.h>
#include <hip/hip_bf16.h>
#include <math.h>

namespace cg = cooperative_groups;

#define B_ 4
#define T_ 2048
#define C_ 1024
#define H_ 16
#define D_ 64
#define BT (B_*T_)
#define BH (B_*H_)

typedef __bf16 bf16x8 __attribute__((ext_vector_type(8)));
typedef __bf16 bf16x4 __attribute__((ext_vector_type(4)));
typedef float f32x4 __attribute__((ext_vector_type(4)));
typedef unsigned short u16;
typedef u16 u16x8 __attribute__((ext_vector_type(8)));

// async global->LDS, 16B/lane; LDS dest = wave-uniform base + lane*16
#define GLL(g, l) __builtin_amdgcn_global_load_lds( \
    (const __attribute__((address_space(1))) unsigned int*)(g), \
    (__attribute__((address_space(3))) unsigned int*)(l), 16, 0, 0)

#define SCALE2 0.04508422f  // C^-0.5 * log2(e), folded into Wq

__device__ __forceinline__ u16 f2b(float f) {
    union { float f; unsigned u; } v; v.f = f;
    unsigned r = v.u + 0x7fffu + ((v.u >> 16) & 1u);
    return (u16)(r >> 16);
}

// ================= single fused cooperative kernel =========================
// 512 persistent blocks x 256 threads; 4 phases separated by grid.sync().
// LDS: 51200 B union — prep transpose [64][72]; GEMM Al/Bl [128][64]x2;
// attn Kl/Vl [2][64][64] + Pl [4][32][72].
__global__ void mha_fused(const float* __restrict__ x,
                          const float* __restrict__ Wq,
                          const float* __restrict__ Wk,
                          const float* __restrict__ Wv,
                          const float* __restrict__ Wo,
                          const float* __restrict__ bo,
                          u16* __restrict__ xbf, u16* __restrict__ wobf,
                          u16* __restrict__ wt, u16* __restrict__ qb,
                          u16* __restrict__ kb, u16* __restrict__ vtb,
                          u16* __restrict__ attb, float* __restrict__ out) {
    cg::grid_group grid = cg::this_grid();
    __shared__ __align__(16) unsigned char smem[51200];
    int bid = blockIdx.x, tid = threadIdx.x;
    int wv = tid >> 6, lane = tid & 63, l15 = lane & 15, quad = lane >> 4;

    // ---------------- phase 0: prep --------------------------------------
    {
        u16 (*lds)[72] = (u16(*)[72])smem;
        for (int pb = bid; pb < 9984; pb += 512) {
            if (pb < 8192) {
                int g = pb * 256 + tid;
                float4 v = ((const float4*)x)[g];
                ushort4 o;
                o.x = f2b(v.x); o.y = f2b(v.y); o.z = f2b(v.z); o.w = f2b(v.w);
                ((ushort4*)xbf)[g] = o;
            } else if (pb < 9216) {
                int g = (pb - 8192) * 256 + tid;
                float4 v = ((const float4*)Wo)[g];
                ushort4 o;
                o.x = f2b(v.x); o.y = f2b(v.y); o.z = f2b(v.z); o.w = f2b(v.w);
                ((ushort4*)wobf)[g] = o;
            } else {
                int id = pb - 9216;              // 0..767
                int cb = id & 15, h = (id >> 4) & 15, w = id >> 8;
                const float* W = (w == 0) ? Wq : (w == 1) ? Wk : Wv;
                float sc = (w == 0) ? SCALE2 : 1.0f;
                int c0 = cb * 64;
                {
                    int col = (tid & 15) * 4;
                    for (int cc = 0; cc < 4; ++cc) {
                        int r = (tid >> 4) + cc * 16;
                        float4 v = *(const float4*)&W[(size_t)(h * C_ + c0 + r) * D_ + col];
                        lds[r][col + 0] = f2b(v.x * sc); lds[r][col + 1] = f2b(v.y * sc);
                        lds[r][col + 2] = f2b(v.z * sc); lds[r][col + 3] = f2b(v.w * sc);
                    }
                }
                __syncthreads();
                {
                    int tcol = (tid & 7) * 8;
                    for (int cc = 0; cc < 2; ++cc) {
                        int d = (tid >> 3) + cc * 32;
                        u16x8 t;
                        for (int j = 0; j < 8; ++j) t[j] = lds[tcol + j][d];
                        *(u16x8*)&wt[(((size_t)(w * H_ + h) * D_ + d) * C_) + c0 + tcol] = t;
                    }
                }
                __syncthreads();   // protect lds before next transpose iter
            }
        }
    }
    __threadfence();
    grid.sync();

    // ---------------- phase 1: fused QKV GEMM ----------------------------
    // x[8192,1024] x wt[3072,1024]^T -> q,k [BH,T,D]; V transposed to vt[BH,D,T]
    {
        u16 (*Al)[64] = (u16(*)[64])smem;
        u16 (*Bl)[64] = (u16(*)[64])(smem + 32768);
        int rowh = (wv & 1) * 64, colh = (wv >> 1) * 64;
        int lrow = lane >> 3;
        int scol = (((lane & 7) ^ lrow)) * 8;       // swizzled source column
        int rsw = l15 & 7;                          // read-side swizzle key
        for (int t = bid; t < 1536; t += 512) {
            int mb = t & 63, nb = t >> 6;
            f32x4 acc[4][4];
            #pragma unroll
            for (int i = 0; i < 4; ++i)
                #pragma unroll
                for (int j = 0; j < 4; ++j) acc[i][j] = (f32x4){0.f, 0.f, 0.f, 0.f};
            int srow = wv * 32 + lrow;
            const u16* agp = &xbf[(size_t)(mb * 128 + srow) * C_ + scol];
            const u16* bgp = &wt[(size_t)(nb * 128 + srow) * C_ + scol];
            for (int k0 = 0; k0 < C_; k0 += 64) {
                #pragma unroll
                for (int j = 0; j < 4; ++j) {
                    GLL(agp + (size_t)(j * 8) * C_ + k0, &Al[wv * 32 + j * 8][0]);
                    GLL(bgp + (size_t)(j * 8) * C_ + k0, &Bl[wv * 32 + j * 8][0]);
                }
                __syncthreads();
                #pragma unroll
                for (int ks = 0; ks < 2; ++ks) {
                    int cbl = (((ks << 2) | quad) ^ rsw) * 8;
                    bf16x8 af[4], bf[4];
                    #pragma unroll
                    for (int mt = 0; mt < 4; ++mt)
                        af[mt] = *(const bf16x8*)&Al[rowh + mt * 16 + l15][cbl];
                    #pragma unroll
                    for (int nt = 0; nt < 4; ++nt)
                        bf[nt] = *(const bf16x8*)&Bl[colh + nt * 16 + l15][cbl];
                    #pragma unroll
                    for (int mt = 0; mt < 4; ++mt)
                        #pragma unroll
                        for (int nt = 0; nt < 4; ++nt)
                            acc[mt][nt] = __builtin_amdgcn_mfma_f32_16x16x32_bf16(af[mt], bf[nt], acc[mt][nt], 0, 0, 0);
                }
                __syncthreads();
            }
            int bb = (mb * 128) >> 11;        // whole tile is one batch
            #pragma unroll
            for (int nt = 0; nt < 4; ++nt) {
                int n0 = nb * 128 + colh + nt * 16;
                int wsel = n0 >> 10, hh = (n0 >> 6) & 15, d0 = n0 & 63;
                if (wsel == 2) {
                    u16* vrow = vtb + ((size_t)((bb * H_ + hh) * D_) + d0 + l15) * T_;
                    #pragma unroll
                    for (int mt = 0; mt < 4; ++mt) {
                        int tbase = ((mb * 128 + rowh + mt * 16) & (T_ - 1)) + quad * 4;
                        bf16x4 w;
                        #pragma unroll
                        for (int r = 0; r < 4; ++r) w[r] = (__bf16)acc[mt][nt][r];
                        *(bf16x4*)&vrow[tbase] = w;
                    }
                } else {
                    u16* op = (wsel == 0) ? qb : kb;
                    #pragma unroll
                    for (int mt = 0; mt < 4; ++mt)
                        #pragma unroll
                        for (int r = 0; r < 4; ++r) {
                            int m = mb * 128 + rowh + mt * 16 + quad * 4 + r;
                            int tt = m & (T_ - 1);
                            op[((size_t)(bb * H_ + hh) * T_ + tt) * D_ + d0 + l15] = f2b(acc[mt][nt][r]);
                        }
                }
            }
            __syncthreads();   // LDS safe before next tile's staging
        }
    }
    __threadfence();
    grid.sync();

    // ---------------- phase 2: flash attention (fixed-base softmax) -------
    // 2 chunks per block, paired (bid, 1023-bid) -> uniform 34 KV-tiles/block.
    {
        u16 (*Kl)[64][64] = (u16(*)[64][64])smem;
        u16 (*Vl)[64][64] = (u16(*)[64][64])(smem + 16384);
        u16 (*Pl)[32][72] = (u16(*)[32][72])(smem + 32768);
        u16* pw = &Pl[wv][0][0];
        bf16x8 ones;
        #pragma unroll
        for (int j = 0; j < 8; ++j) ones[j] = (__bf16)1.0f;
        int r8 = lane >> 3, cbl_st = lane & 7;
        int csrc = ((cbl_st ^ r8)) * 8;
        int strow = wv * 16 + r8;
        int rsw = l15 & 7;
        for (int ti = 0; ti < 2; ++ti) {
            int t = ti ? (1023 - bid) : bid;
            int bh = t & 63, c = 15 - (t >> 6);
            int b = bh >> 4, h = bh & 15;
            const u16* qbase = qb + (size_t)bh * T_ * D_;
            const u16* kbase = kb + (size_t)bh * T_ * D_;
            const u16* vbase = vtb + (size_t)bh * D_ * T_;
            int R0q = c * 128 + wv * 32;
            int ktb = 2 * c + 1;
            int kmax_w = R0q >> 6;
            bf16x8 bq[2][2];
            #pragma unroll
            for (int qt = 0; qt < 2; ++qt)
                #pragma unroll
                for (int kd = 0; kd < 2; ++kd)
                    bq[qt][kd] = *(const bf16x8*)&qbase[(size_t)(R0q + qt * 16 + l15) * D_ + kd * 32 + quad * 8];
            f32x4 o[4][2];
            f32x4 lacc[2];
            #pragma unroll
            for (int dt = 0; dt < 4; ++dt)
                #pragma unroll
                for (int qt = 0; qt < 2; ++qt) o[dt][qt] = (f32x4){0.f, 0.f, 0.f, 0.f};
            lacc[0] = (f32x4){0.f, 0.f, 0.f, 0.f};
            lacc[1] = (f32x4){0.f, 0.f, 0.f, 0.f};
            #pragma unroll
            for (int j = 0; j < 2; ++j) {
                GLL(kbase + (size_t)(strow + j * 8) * D_ + csrc, &Kl[0][wv * 16 + j * 8][0]);
                GLL(vbase + (size_t)(strow + j * 8) * T_ + csrc, &Vl[0][wv * 16 + j * 8][0]);
            }
            __syncthreads();
            for (int kt = 0; kt <= ktb; ++kt) {
                int cur = kt & 1;
                if (kt < ktb) {
                    int kn = (kt + 1) * 64;
                    #pragma unroll
                    for (int j = 0; j < 2; ++j) {
                        GLL(kbase + (size_t)(kn + strow + j * 8) * D_ + csrc, &Kl[cur ^ 1][wv * 16 + j * 8][0]);
                        GLL(vbase + (size_t)(strow + j * 8) * T_ + kn + csrc, &Vl[cur ^ 1][wv * 16 + j * 8][0]);
                    }
                }
                if (kt <= kmax_w) {
                    int k0 = kt * 64;
                    f32x4 sS[4][2];
                    #pragma unroll
                    for (int kvt = 0; kvt < 4; ++kvt)
                        #pragma unroll
                        for (int qt = 0; qt < 2; ++qt) sS[kvt][qt] = (f32x4){0.f, 0.f, 0.f, 0.f};
                    #pragma unroll
                    for (int kd = 0; kd < 2; ++kd) {
                        int cblk = (((kd << 2) | quad) ^ rsw) * 8;
                        bf16x8 akf[4];
                        #pragma unroll
                        for (int kvt = 0; kvt < 4; ++kvt)
                            akf[kvt] = *(const bf16x8*)&Kl[cur][kvt * 16 + l15][cblk];
                        #pragma unroll
                        for (int kvt = 0; kvt < 4; ++kvt)
                            #pragma unroll
                            for (int qt = 0; qt < 2; ++qt)
                                sS[kvt][qt] = __builtin_amdgcn_mfma_f32_16x16x32_bf16(akf[kvt], bq[qt][kd], sS[kvt][qt], 0, 0, 0);
                    }
                    if (kt == kmax_w) {  // causal mask, diagonal tile only
                        #pragma unroll
                        for (int qt = 0; qt < 2; ++qt) {
                            int qabs = R0q + qt * 16 + l15;
                            #pragma unroll
                            for (int kvt = 0; kvt < 4; ++kvt) {
                                int kvb = k0 + kvt * 16 + quad * 4;
                                #pragma unroll
                                for (int r = 0; r < 4; ++r)
                                    if (kvb + r > qabs) sS[kvt][qt][r] = -INFINITY;
                            }
                        }
                    }
                    #pragma unroll
                    for (int kvt = 0; kvt < 4; ++kvt)
                        #pragma unroll
                        for (int qt = 0; qt < 2; ++qt)
                            #pragma unroll
                            for (int r = 0; r < 4; ++r)
                                sS[kvt][qt][r] = __builtin_amdgcn_exp2f(sS[kvt][qt][r]);
                    #pragma unroll
                    for (int qt = 0; qt < 2; ++qt)
                        #pragma unroll
                        for (int kvt = 0; kvt < 4; ++kvt) {
                            bf16x4 w;
                            #pragma unroll
                            for (int r = 0; r < 4; ++r) w[r] = (__bf16)sS[kvt][qt][r];
                            *(bf16x4*)&pw[(qt * 16 + l15) * 72 + kvt * 16 + quad * 4] = w;
                        }
                    #pragma unroll
                    for (int ks = 0; ks < 2; ++ks) {
                        int cblk = (((ks << 2) | quad) ^ rsw) * 8;
                        bf16x8 avf[4];
                        #pragma unroll
                        for (int dt = 0; dt < 4; ++dt)
                            avf[dt] = *(const bf16x8*)&Vl[cur][dt * 16 + l15][cblk];
                        #pragma unroll
                        for (int qt = 0; qt < 2; ++qt) {
                            bf16x8 bp = *(const bf16x8*)&pw[(qt * 16 + l15) * 72 + ks * 32 + quad * 8];
                            #pragma unroll
                            for (int dt = 0; dt < 4; ++dt)
                                o[dt][qt] = __builtin_amdgcn_mfma_f32_16x16x32_bf16(avf[dt], bp, o[dt][qt], 0, 0, 0);
                            lacc[qt] = __builtin_amdgcn_mfma_f32_16x16x32_bf16(ones, bp, lacc[qt], 0, 0, 0);
                        }
                    }
                }
                __syncthreads();
            }
            #pragma unroll
            for (int qt = 0; qt < 2; ++qt) {
                float rl = __builtin_amdgcn_rcpf(lacc[qt][0]);
                int qabs = R0q + qt * 16 + l15;
                #pragma unroll
                for (int dt = 0; dt < 4; ++dt) {
                    bf16x4 w;
                    #pragma unroll
                    for (int r = 0; r < 4; ++r) w[r] = (__bf16)(o[dt][qt][r] * rl);
                    *(bf16x4*)&attb[(size_t)(b * T_ + qabs) * C_ + h * 64 + dt * 16 + quad * 4] = w;
                }
            }
        }
    }
    __threadfence();
    grid.sync();

    // ---------------- phase 3: out projection -----------------------------
    // att[8192,1024] x wo[1024,1024]^T + bo -> fp32 out; 512 tiles exactly.
    {
        u16 (*Al)[64] = (u16(*)[64])smem;
        u16 (*Bl)[64] = (u16(*)[64])(smem + 32768);
        int mb = bid & 63, nb = bid >> 6;
        int rowh = (wv & 1) * 64, colh = (wv >> 1) * 64;
        f32x4 acc[4][4];
        #pragma unroll
        for (int i = 0; i < 4; ++i)
            #pragma unroll
            for (int j = 0; j < 4; ++j) acc[i][j] = (f32x4){0.f, 0.f, 0.f, 0.f};
        int lrow = lane >> 3;
        int srow = wv * 32 + lrow;
        int scol = (((lane & 7) ^ lrow)) * 8;
        const u16* agp = &attb[(size_t)(mb * 128 + srow) * C_ + scol];
        const u16* bgp = &wobf[(size_t)(nb * 128 + srow) * C_ + scol];
        int rsw = l15 & 7;
        for (int k0 = 0; k0 < C_; k0 += 64) {
            #pragma unroll
            for (int j = 0; j < 4; ++j) {
                GLL(agp + (size_t)(j * 8) * C_ + k0, &Al[wv * 32 + j * 8][0]);
                GLL(bgp + (size_t)(j * 8) * C_ + k0, &Bl[wv * 32 + j * 8][0]);
            }
            __syncthreads();
            #pragma unroll
            for (int ks = 0; ks < 2; ++ks) {
                int cbl = (((ks << 2) | quad) ^ rsw) * 8;
                bf16x8 af[4], bf[4];
                #pragma unroll
                for (int mt = 0; mt < 4; ++mt)
                    af[mt] = *(const bf16x8*)&Al[rowh + mt * 16 + l15][cbl];
                #pragma unroll
                for (int nt = 0; nt < 4; ++nt)
                    bf[nt] = *(const bf16x8*)&Bl[colh + nt * 16 + l15][cbl];
                #pragma unroll
                for (int mt = 0; mt < 4; ++mt)
                    #pragma unroll
                    for (int nt = 0; nt < 4; ++nt)
                        acc[mt][nt] = __builtin_amdgcn_mfma_f32_16x16x32_bf16(af[mt], bf[nt], acc[mt][nt], 0, 0, 0);
            }
            __syncthreads();
        }
        #pragma unroll
        for (int nt = 0; nt < 4; ++nt) {
            int n = nb * 128 + colh + nt * 16 + l15;
            float bias = bo[n];
            #pragma unroll
            for (int mt = 0; mt < 4; ++mt)
                #pragma unroll
                for (int r = 0; r < 4; ++r) {
                    int m = mb * 128 + rowh + mt * 16 + quad * 4 + r;
                    out[(size_t)m * C_ + n] = acc[mt][nt][r] + bias;
                }
        }
    }
}

extern "C" void kernel_launch(void* const* d_in, const int* in_sizes, int n_in,
                              void* d_out, int out_size, void* d_ws, size_t ws_size,
                              hipStream_t stream) {
    const float* x  = (const float*)d_in[0];
    const float* Wq = (const float*)d_in[1];
    const float* Wk = (const float*)d_in[2];
    const float* Wv = (const float*)d_in[3];
    const float* Wo = (const float*)d_in[4];
    const float* bo = (const float*)d_in[5];
    float* outp = (float*)d_out;
    char* ws = (char*)d_ws;
    u16* xbf  = (u16*)(ws + (size_t)0);           // 16 MB  x bf16 [8192,1024]
    u16* wt   = (u16*)(ws + ((size_t)16 << 20));  //  6 MB  W qkv [3072,1024] bf16
    u16* wobf = (u16*)(ws + ((size_t)22 << 20));  //  2 MB  Wo bf16 [1024,1024]
    u16* qb   = (u16*)(ws + ((size_t)24 << 20));  // 16 MB  q [BH,T,D]
    u16* kb   = (u16*)(ws + ((size_t)40 << 20));  // 16 MB  k [BH,T,D]
    u16* vtb  = (u16*)(ws + ((size_t)56 << 20));  // 16 MB  v^T [BH,D,T]
    u16* attb = (u16*)(ws + ((size_t)72 << 20));  // 16 MB  att out [B*T,C]

    void* args[] = {&x, &Wq, &Wk, &Wv, &Wo, &bo,
                    &xbf, &wobf, &wt, &qb, &kb, &vtb, &attb, &outp};
    hipLaunchCooperativeKernel((const void*)mha_fused, dim3(512), dim3(256),
                               args, 0, stream);
}